// Round 11
// baseline (30.417 us; speedup 1.0000x reference)
//
#include <hip/hip_runtime.h>
#include <math.h>

// SegmentTreeAttention — MI355X (gfx950), round 11.
// B=16, S=8192, D=64, N=32, LEVELS=5. f32 in/out. valid_lens per-batch.
//
// VALU-issue-bound (r10 confirmed). This round: SCALAR-DOT DESCENT.
//   q.(P[m]-P[a]) = q.P[m] - q.P[a]  (linearity)
// Keep scalar frontier dots dotA/dotR; per level compute ONE new dot
// dotM = q.P[cm] (16 FMA + 3 DPP per query) and form both scores as
// scalar subtracts. Frontier updates become scalar cndmasks (was 16
// vector cndmasks); ~24 VGPR freed.
// cond protection: fast scores deviate from r10-exact by <~2.4e-4
// worst-case; gray window (|sL-sR| < 2e-3, or dn-band 1e-3) triggers a
// rescue under __any() (~1% of wave-levels) that re-reads the frontier
// rows (offsets tracked) and recomputes EXACTLY r10's subtract-then-dot
// + exact-IEEE-div cond. So cond == r10's validated decisions; weights
// shift by ~1e-5 (threshold 0.12, ours 0.0156).
// Keeps: QPB=64, 2-query ILP, DPP reduce, clamp identity, rcp weights,
// byte-offset deferred gather, q-load hoist, no launch-bounds cap.

#define SEG_N   32
#define DIM     64
#define LEVELS  5
#define QPB     64      // queries per block
#define THREADS 256
#define PAD     68      // LDS row stride in dwords
#define PADB    (PAD * 4)

#define DPP_QUAD_XOR1   0xB1    // quad_perm [1,0,3,2]
#define DPP_QUAD_XOR2   0x4E    // quad_perm [2,3,0,1]
#define DPP_ROW_HMIRROR 0x141   // row_half_mirror (lane p -> 7-p within 8)

#if __has_builtin(__builtin_amdgcn_rcpf)
#define RCPF(x) __builtin_amdgcn_rcpf(x)
#else
#define RCPF(x) (1.0f / (x))
#endif

template <int CTRL>
__device__ __forceinline__ float dpp_xadd(float v) {
    const int s = __builtin_amdgcn_update_dpp(0, __float_as_int(v), CTRL, 0xf, 0xf, true);
    return v + __int_as_float(s);
}

// 8-lane group sum, all lanes get the bit-identical total.
__device__ __forceinline__ float group8_sum(float v) {
    v = dpp_xadd<DPP_QUAD_XOR1>(v);
    v = dpp_xadd<DPP_QUAD_XOR2>(v);
    v = dpp_xadd<DPP_ROW_HMIRROR>(v);
    return v;
}

__device__ __forceinline__ float4 f4sub(const float4 a, const float4 b) {
    return make_float4(a.x - b.x, a.y - b.y, a.z - b.z, a.w - b.w);
}
__device__ __forceinline__ float dot4(const float4 a, const float4 b) {
    return a.x * b.x + a.y * b.y + a.z * b.z + a.w * b.w;
}
__device__ __forceinline__ void fma4(float4& acc, const float4 hi, const float4 lo, float w) {
    acc.x = fmaf(hi.x - lo.x, w, acc.x);
    acc.y = fmaf(hi.y - lo.y, w, acc.y);
    acc.z = fmaf(hi.z - lo.z, w, acc.z);
    acc.w = fmaf(hi.w - lo.w, w, acc.w);
}

__global__ __launch_bounds__(THREADS) void segtree_attn_kernel(
    const float* __restrict__ q,
    const float* __restrict__ keys,
    const float* __restrict__ values,
    const int*   __restrict__ vlen,
    float*       __restrict__ out,
    int S)
{
    __shared__ float P[2][SEG_N * PAD];   // P[0]=Pk, P[1]=Pv

    const int b = blockIdx.y;
    const int t = threadIdx.x;
    const int g = t >> 3;           // query group within block (0..31)
    const int u = t & 7;            // lane within group
    const int c = u * 8;            // column base (2x float4)
    const int c4 = c * 4;           // byte offset of column base

    const int sA = blockIdx.x * QPB + g;
    const int sB = sA + 32;

    // ---- q loads hoisted: latency hides under staging + barrier ----
    const float* qpA = q + ((size_t)b * S + sA) * DIM + c;
    const float* qpB = q + ((size_t)b * S + sB) * DIM + c;
    const float4 qA0 = *(const float4*)qpA;
    const float4 qA1 = *(const float4*)(qpA + 4);
    const float4 qB0 = *(const float4*)qpB;
    const float4 qB1 = *(const float4*)(qpB + 4);

    // ---- Stage prefix sums into LDS: P[0]=0, P[m]=sum_{l=1..m} x[l] ----
    if (t < 2 * DIM) {
        const int col = t & (DIM - 1);
        const float* src = ((t < DIM) ? keys : values) + (size_t)b * SEG_N * DIM + col;
        float* dst = (t < DIM) ? P[0] : P[1];
        float acc = 0.0f;
        dst[col] = 0.0f;
        #pragma unroll
        for (int row = 1; row < SEG_N; ++row) {
            acc += src[row * DIM];
            dst[row * PAD + col] = acc;
        }
    }
    const int n = vlen[b];          // block-uniform (valid_lens is [B])
    __syncthreads();

    const int hnc = max(min(n - 1, SEG_N - 1), 0);
    const float scale[LEVELS] = {0.0625f, 0.125f, 0.25f, 0.5f, 1.0f};
    const char* Kb = (const char*)&P[0][0];
    const char* Vb = (const char*)&P[1][0];

    // ---- prologue: frontier dots. dotA = q.P[0] = 0 exactly. ----
    const int offN = hnc * PADB + c4;
    const float4 pkN0 = *(const float4*)(Kb + offN);
    const float4 pkN1 = *(const float4*)(Kb + offN + 16);
    float dotR_A = group8_sum(dot4(qA0, pkN0) + dot4(qA1, pkN1));
    float dotR_B = group8_sum(dot4(qB0, pkN0) + dot4(qB1, pkN1));
    float dotA_A = 0.0f, dotA_B = 0.0f;

    int offA_A = c4, offR_A = offN;     // byte offsets of frontier rows
    int offA_B = c4, offR_B = offN;
    int midA = 16, midB = 16;
    int lA = 1, rA = SEG_N;
    int lB = 1, rB = SEG_N;

    float wA[LEVELS], wB[LEVELS];
    unsigned int rowsA[LEVELS], rowsB[LEVELS];   // hiOff | loOff<<16

    #pragma unroll
    for (int lev = 0; lev < LEVELS; ++lev) {
        const int step = 8 >> lev;
        const int cmA = min(midA, hnc);     // clamped row (clamp identity)
        const int cmB = min(midB, hnc);
        const int offMA = cmA * PADB + c4;
        const int offMB = cmB * PADB + c4;

        const float4 mA0 = *(const float4*)(Kb + offMA);
        const float4 mA1 = *(const float4*)(Kb + offMA + 16);
        const float4 mB0 = *(const float4*)(Kb + offMB);
        const float4 mB1 = *(const float4*)(Kb + offMB + 16);

        const float dotM_A = group8_sum(dot4(qA0, mA0) + dot4(qA1, mA1));
        const float dotM_B = group8_sum(dot4(qB0, mB0) + dot4(qB1, mB1));

        const bool okLA = (min(midA, n - 1) >= lA);
        const bool okRA = (min(rA,   n - 1) >= midA + 1);
        const bool okLB = (min(midB, n - 1) >= lB);
        const bool okRB = (min(rB,   n - 1) >= midB + 1);

        // fast scores: dot-then-subtract (deviation from exact < ~2.4e-4)
        const float sLA = okLA ? (dotM_A - dotA_A) : 0.0f;
        const float sRA = okRA ? (dotR_A - dotM_A) : 0.0f;
        const float sLB = okLB ? (dotM_B - dotA_B) : 0.0f;
        const float sRB = okRB ? (dotR_B - dotM_B) : 0.0f;

        float dnLA = 1.0f + __expf(-sLA);
        float dnRA = 1.0f + __expf(-sRA);
        float dnLB = 1.0f + __expf(-sLB);
        float dnRB = 1.0f + __expf(-sRB);

        bool condA = (dnLA <= dnRA);
        bool condB = (dnLB <= dnRB);

        // gray: fast decision might differ from exact path -> rescue
        const bool grayA = (__builtin_fabsf(sLA - sRA) < 2e-3f) ||
                           ((dnLA > dnRA) && (dnLA - dnRA < dnLA * 1e-3f));
        const bool grayB = (__builtin_fabsf(sLB - sRB) < 2e-3f) ||
                           ((dnLB > dnRB) && (dnLB - dnRB < dnLB * 1e-3f));
        if (__any(grayA || grayB)) {
            // EXACT r10 path: subtract-then-dot, DPP, exact IEEE divs.
            const float4 fA0 = *(const float4*)(Kb + offA_A);
            const float4 fA1 = *(const float4*)(Kb + offA_A + 16);
            const float4 gA0 = *(const float4*)(Kb + offR_A);
            const float4 gA1 = *(const float4*)(Kb + offR_A + 16);
            float dLx = dot4(qA0, f4sub(mA0, fA0)) + dot4(qA1, f4sub(mA1, fA1));
            float dRx = dot4(qA0, f4sub(gA0, mA0)) + dot4(qA1, f4sub(gA1, mA1));
            dLx = group8_sum(dLx);
            dRx = group8_sum(dRx);
            dnLA = 1.0f + __expf(-(okLA ? dLx : 0.0f));
            dnRA = 1.0f + __expf(-(okRA ? dRx : 0.0f));
            condA = ((1.0f / dnLA) >= (1.0f / dnRA));

            const float4 fB0 = *(const float4*)(Kb + offA_B);
            const float4 fB1 = *(const float4*)(Kb + offA_B + 16);
            const float4 gB0 = *(const float4*)(Kb + offR_B);
            const float4 gB1 = *(const float4*)(Kb + offR_B + 16);
            float dLy = dot4(qB0, f4sub(mB0, fB0)) + dot4(qB1, f4sub(mB1, fB1));
            float dRy = dot4(qB0, f4sub(gB0, mB0)) + dot4(qB1, f4sub(gB1, mB1));
            dLy = group8_sum(dLy);
            dRy = group8_sum(dRy);
            dnLB = 1.0f + __expf(-(okLB ? dLy : 0.0f));
            dnRB = 1.0f + __expf(-(okRB ? dRy : 0.0f));
            condB = ((1.0f / dnLB) >= (1.0f / dnRB));
        }

        const bool  okselA = condA ? okRA : okLA;
        const bool  okselB = condB ? okRB : okLB;
        const float wselA  = RCPF(condA ? dnRA : dnLA);  // weight: <=1ulp
        const float wselB  = RCPF(condB ? dnRB : dnLB);
        wA[lev] = okselA ? (wselA * scale[lev]) : 0.0f;  // pow2 scale: exact
        wB[lev] = okselB ? (wselB * scale[lev]) : 0.0f;

        const unsigned int hiA = condA ? offR_A : offMA;
        const unsigned int loA = condA ? offMA  : offA_A;
        const unsigned int hiB = condB ? offR_B : offMB;
        const unsigned int loB = condB ? offMB  : offA_B;
        rowsA[lev] = hiA | (loA << 16);
        rowsB[lev] = hiB | (loB << 16);

        // scalar frontier updates (use OLD mid for l/r)
        dotA_A = condA ? dotA_A : dotM_A;
        dotR_A = condA ? dotM_A : dotR_A;
        offA_A = condA ? offA_A : offMA;
        offR_A = condA ? offMA  : offR_A;
        rA = condA ? midA : rA;
        lA = condA ? lA : (midA + 1);

        dotA_B = condB ? dotA_B : dotM_B;
        dotR_B = condB ? dotM_B : dotR_B;
        offA_B = condB ? offA_B : offMB;
        offR_B = condB ? offMB  : offR_B;
        rB = condB ? midB : rB;
        lB = condB ? lB : (midB + 1);

        if (lev < LEVELS - 1) {
            midA = condA ? (midA - step) : (midA + step);
            midB = condB ? (midB - step) : (midB + step);
        }
    }

    // ---- deferred value gather: ans = sum_lev w * (Pv[hi] - Pv[lo]) ----
    float4 aA0 = make_float4(0.f,0.f,0.f,0.f), aA1 = make_float4(0.f,0.f,0.f,0.f);
    float4 aB0 = make_float4(0.f,0.f,0.f,0.f), aB1 = make_float4(0.f,0.f,0.f,0.f);
    #pragma unroll
    for (int lev = 0; lev < LEVELS; ++lev) {
        const unsigned int pa = rowsA[lev];
        const unsigned int pb = rowsB[lev];
        const unsigned int hiA = pa & 0xFFFFu, loA = pa >> 16;
        const unsigned int hiB = pb & 0xFFFFu, loB = pb >> 16;
        const float4 hA0 = *(const float4*)(Vb + hiA);
        const float4 hA1 = *(const float4*)(Vb + hiA + 16);
        const float4 lA0 = *(const float4*)(Vb + loA);
        const float4 lA1 = *(const float4*)(Vb + loA + 16);
        fma4(aA0, hA0, lA0, wA[lev]);
        fma4(aA1, hA1, lA1, wA[lev]);
        const float4 hB0 = *(const float4*)(Vb + hiB);
        const float4 hB1 = *(const float4*)(Vb + hiB + 16);
        const float4 lB0 = *(const float4*)(Vb + loB);
        const float4 lB1 = *(const float4*)(Vb + loB + 16);
        fma4(aB0, hB0, lB0, wB[lev]);
        fma4(aB1, hB1, lB1, wB[lev]);
    }

    float* opA = out + ((size_t)b * S + sA) * DIM + c;
    float* opB = out + ((size_t)b * S + sB) * DIM + c;
    *(float4*)opA       = aA0;
    *(float4*)(opA + 4) = aA1;
    *(float4*)opB       = aB0;
    *(float4*)(opB + 4) = aB1;
}

extern "C" void kernel_launch(void* const* d_in, const int* in_sizes, int n_in,
                              void* d_out, int out_size, void* d_ws, size_t ws_size,
                              hipStream_t stream) {
    const float* q    = (const float*)d_in[0];
    const float* keys = (const float*)d_in[1];
    const float* vals = (const float*)d_in[2];
    const int*   vl   = (const int*)d_in[3];
    float* out = (float*)d_out;

    const int B = in_sizes[3];                 // 16
    const int S = in_sizes[0] / (B * DIM);     // 8192

    dim3 grid(S / QPB, B);
    segtree_attn_kernel<<<grid, THREADS, 0, stream>>>(q, keys, vals, vl, out, S);
}

// Round 12
// 28.620 us; speedup vs baseline: 1.0628x; 1.0628x over previous
//
#include <hip/hip_runtime.h>
#include <math.h>

// SegmentTreeAttention — MI355X (gfx950), round 12.
// B=16, S=8192, D=64, N=32, LEVELS=5. f32 in/out. valid_lens per-batch.
//
// r11 (scalar-dot + rescue) regressed -> reverted to r10 (24.6us best).
// Pipe model: LDS pipe ~11us of 24.6 (80 b128-equiv/thread), VALU ~9us;
// the deferred Pv gather is 50% of LDS ops + a 225-instr serial tail.
// This round = r8's HW-validated INLINE-Pv accumulation (register
// frontiers pvA/pvR, ans += w*(hi-lo) in level order) grafted onto
// r10's frame (QPB=64, div-free cond, rcp weights, byte offsets):
//   - per level: read Pk[cm] + Pv[cm] (4 b128), no gather phase at all.
//   - LDS ops/query 30 -> 20; block tail = just the stores.
//   - cost: VGPR ~85 -> ~115 (frontier regs); accepted risk.
// Numerics: union of r10 (staging, subtract-then-dot, DPP reduce,
// dn-compare cond + gray rescue, rcp weights, pow2 scales) and r8
// (inline value accumulation) — both passed with absmax 0.015625.

#define SEG_N   32
#define DIM     64
#define LEVELS  5
#define QPB     64      // queries per block
#define THREADS 256
#define PAD     68      // LDS row stride in dwords
#define PADB    (PAD * 4)

#define DPP_QUAD_XOR1   0xB1    // quad_perm [1,0,3,2]
#define DPP_QUAD_XOR2   0x4E    // quad_perm [2,3,0,1]
#define DPP_ROW_HMIRROR 0x141   // row_half_mirror (lane p -> 7-p within 8)

#if __has_builtin(__builtin_amdgcn_rcpf)
#define RCPF(x) __builtin_amdgcn_rcpf(x)
#else
#define RCPF(x) (1.0f / (x))
#endif

template <int CTRL>
__device__ __forceinline__ float dpp_xadd(float v) {
    const int s = __builtin_amdgcn_update_dpp(0, __float_as_int(v), CTRL, 0xf, 0xf, true);
    return v + __int_as_float(s);
}

// 8-lane group sum, all lanes get the bit-identical total.
__device__ __forceinline__ float group8_sum(float v) {
    v = dpp_xadd<DPP_QUAD_XOR1>(v);
    v = dpp_xadd<DPP_QUAD_XOR2>(v);
    v = dpp_xadd<DPP_ROW_HMIRROR>(v);
    return v;
}

__device__ __forceinline__ float4 f4sub(const float4 a, const float4 b) {
    return make_float4(a.x - b.x, a.y - b.y, a.z - b.z, a.w - b.w);
}
__device__ __forceinline__ float4 sel4(bool c, const float4 a, const float4 b) {
    return make_float4(c ? a.x : b.x, c ? a.y : b.y, c ? a.z : b.z, c ? a.w : b.w);
}
__device__ __forceinline__ float dot4(const float4 a, const float4 b) {
    return a.x * b.x + a.y * b.y + a.z * b.z + a.w * b.w;
}
__device__ __forceinline__ void fma4(float4& acc, const float4 hi, const float4 lo, float w) {
    acc.x = fmaf(hi.x - lo.x, w, acc.x);
    acc.y = fmaf(hi.y - lo.y, w, acc.y);
    acc.z = fmaf(hi.z - lo.z, w, acc.z);
    acc.w = fmaf(hi.w - lo.w, w, acc.w);
}

__global__ __launch_bounds__(THREADS) void segtree_attn_kernel(
    const float* __restrict__ q,
    const float* __restrict__ keys,
    const float* __restrict__ values,
    const int*   __restrict__ vlen,
    float*       __restrict__ out,
    int S)
{
    __shared__ float P[2][SEG_N * PAD];   // P[0]=Pk, P[1]=Pv

    const int b = blockIdx.y;
    const int t = threadIdx.x;
    const int g = t >> 3;           // query group within block (0..31)
    const int u = t & 7;            // lane within group
    const int c = u * 8;            // column base (2x float4)
    const int c4 = c * 4;           // byte offset of column base

    const int sA = blockIdx.x * QPB + g;
    const int sB = sA + 32;

    // ---- q loads hoisted: latency hides under staging + barrier ----
    const float* qpA = q + ((size_t)b * S + sA) * DIM + c;
    const float* qpB = q + ((size_t)b * S + sB) * DIM + c;
    const float4 qA0 = *(const float4*)qpA;
    const float4 qA1 = *(const float4*)(qpA + 4);
    const float4 qB0 = *(const float4*)qpB;
    const float4 qB1 = *(const float4*)(qpB + 4);

    // ---- Stage prefix sums into LDS: P[0]=0, P[m]=sum_{l=1..m} x[l] ----
    if (t < 2 * DIM) {
        const int col = t & (DIM - 1);
        const float* src = ((t < DIM) ? keys : values) + (size_t)b * SEG_N * DIM + col;
        float* dst = (t < DIM) ? P[0] : P[1];
        float acc = 0.0f;
        dst[col] = 0.0f;
        #pragma unroll
        for (int row = 1; row < SEG_N; ++row) {
            acc += src[row * DIM];
            dst[row * PAD + col] = acc;
        }
    }
    const int n = vlen[b];          // block-uniform (valid_lens is [B])
    __syncthreads();

    const int hnc = max(min(n - 1, SEG_N - 1), 0);
    const float scale[LEVELS] = {0.0625f, 0.125f, 0.25f, 0.5f, 1.0f};
    const char* Kb = (const char*)&P[0][0];
    const char* Vb = (const char*)&P[1][0];

    // initial frontiers: P[l-1]=P[0]=0 ; P[clamp(min(r,n-1))] = P[hnc]
    const int offN = hnc * PADB + c4;
    float4 pkR_A0 = *(const float4*)(Kb + offN);
    float4 pkR_A1 = *(const float4*)(Kb + offN + 16);
    float4 pvR_A0 = *(const float4*)(Vb + offN);
    float4 pvR_A1 = *(const float4*)(Vb + offN + 16);
    float4 pkR_B0 = pkR_A0, pkR_B1 = pkR_A1;
    float4 pvR_B0 = pvR_A0, pvR_B1 = pvR_A1;
    float4 pkA_A0 = make_float4(0.f,0.f,0.f,0.f), pkA_A1 = make_float4(0.f,0.f,0.f,0.f);
    float4 pkA_B0 = make_float4(0.f,0.f,0.f,0.f), pkA_B1 = make_float4(0.f,0.f,0.f,0.f);
    float4 pvA_A0 = make_float4(0.f,0.f,0.f,0.f), pvA_A1 = make_float4(0.f,0.f,0.f,0.f);
    float4 pvA_B0 = make_float4(0.f,0.f,0.f,0.f), pvA_B1 = make_float4(0.f,0.f,0.f,0.f);
    float4 ansA0 = make_float4(0.f,0.f,0.f,0.f), ansA1 = make_float4(0.f,0.f,0.f,0.f);
    float4 ansB0 = make_float4(0.f,0.f,0.f,0.f), ansB1 = make_float4(0.f,0.f,0.f,0.f);

    int midA = 16, midB = 16;
    int lA = 1, rA = SEG_N;
    int lB = 1, rB = SEG_N;

    #pragma unroll
    for (int lev = 0; lev < LEVELS; ++lev) {
        const int step = 8 >> lev;
        const int cmA = min(midA, hnc);     // clamped row (clamp identity)
        const int cmB = min(midB, hnc);
        const int offMA = cmA * PADB + c4;
        const int offMB = cmB * PADB + c4;

        const float4 pkM_A0 = *(const float4*)(Kb + offMA);
        const float4 pkM_A1 = *(const float4*)(Kb + offMA + 16);
        const float4 pkM_B0 = *(const float4*)(Kb + offMB);
        const float4 pkM_B1 = *(const float4*)(Kb + offMB + 16);
        const float4 pvM_A0 = *(const float4*)(Vb + offMA);
        const float4 pvM_A1 = *(const float4*)(Vb + offMA + 16);
        const float4 pvM_B0 = *(const float4*)(Vb + offMB);
        const float4 pvM_B1 = *(const float4*)(Vb + offMB + 16);

        // subtract-then-dot (matches reference rounding structure)
        float dLA = dot4(qA0, f4sub(pkM_A0, pkA_A0)) + dot4(qA1, f4sub(pkM_A1, pkA_A1));
        float dRA = dot4(qA0, f4sub(pkR_A0, pkM_A0)) + dot4(qA1, f4sub(pkR_A1, pkM_A1));
        float dLB = dot4(qB0, f4sub(pkM_B0, pkA_B0)) + dot4(qB1, f4sub(pkM_B1, pkA_B1));
        float dRB = dot4(qB0, f4sub(pkR_B0, pkM_B0)) + dot4(qB1, f4sub(pkR_B1, pkM_B1));

        dLA = group8_sum(dLA);
        dRA = group8_sum(dRA);
        dLB = group8_sum(dLB);
        dRB = group8_sum(dRB);

        const bool okLA = (min(midA, n - 1) >= lA);
        const bool okRA = (min(rA,   n - 1) >= midA + 1);
        const bool okLB = (min(midB, n - 1) >= lB);
        const bool okRB = (min(rB,   n - 1) >= midB + 1);

        const float sLA = okLA ? dLA : 0.0f;
        const float sRA = okRA ? dRA : 0.0f;
        const float sLB = okLB ? dLB : 0.0f;
        const float sRB = okRB ? dRB : 0.0f;

        // sigmoid denominators (exact, same __expf as all passing rounds)
        const float dnLA = 1.0f + __expf(-sLA);
        const float dnRA = 1.0f + __expf(-sRA);
        const float dnLB = 1.0f + __expf(-sLB);
        const float dnRB = 1.0f + __expf(-sRB);

        // div-free cond with gray rescue (r10-validated, bit-exact)
        bool condA = (dnLA <= dnRA);
        bool condB = (dnLB <= dnRB);
        const bool grayA = (dnLA > dnRA) && ((dnLA - dnRA) < dnLA * 1e-6f);
        const bool grayB = (dnLB > dnRB) && ((dnLB - dnRB) < dnLB * 1e-6f);
        if (__any(grayA || grayB)) {        // P ~ 1e-5 per wave-level
            condA = ((1.0f / dnLA) >= (1.0f / dnRA));
            condB = ((1.0f / dnLB) >= (1.0f / dnRB));
        }

        const bool  okselA = condA ? okRA : okLA;
        const bool  okselB = condB ? okRB : okLB;
        const float wselA  = RCPF(condA ? dnRA : dnLA);  // weight: <=1ulp
        const float wselB  = RCPF(condB ? dnRB : dnLB);
        const float wAv = okselA ? (wselA * scale[lev]) : 0.0f;  // pow2: exact
        const float wBv = okselB ? (wselB * scale[lev]) : 0.0f;

        // inline value accumulation (r8-validated): ans += w * (hi - lo)
        const float4 hiA0 = sel4(condA, pvR_A0, pvM_A0);
        const float4 hiA1 = sel4(condA, pvR_A1, pvM_A1);
        const float4 loA0 = sel4(condA, pvM_A0, pvA_A0);
        const float4 loA1 = sel4(condA, pvM_A1, pvA_A1);
        fma4(ansA0, hiA0, loA0, wAv);
        fma4(ansA1, hiA1, loA1, wAv);
        const float4 hiB0 = sel4(condB, pvR_B0, pvM_B0);
        const float4 hiB1 = sel4(condB, pvR_B1, pvM_B1);
        const float4 loB0 = sel4(condB, pvM_B0, pvA_B0);
        const float4 loB1 = sel4(condB, pvM_B1, pvA_B1);
        fma4(ansB0, hiB0, loB0, wBv);
        fma4(ansB1, hiB1, loB1, wBv);

        if (condA) {
            rA = midA;
            pkR_A0 = pkM_A0; pkR_A1 = pkM_A1;
            pvR_A0 = pvM_A0; pvR_A1 = pvM_A1;
        } else {
            lA = midA + 1;
            pkA_A0 = pkM_A0; pkA_A1 = pkM_A1;
            pvA_A0 = pvM_A0; pvA_A1 = pvM_A1;
        }
        if (condB) {
            rB = midB;
            pkR_B0 = pkM_B0; pkR_B1 = pkM_B1;
            pvR_B0 = pvM_B0; pvR_B1 = pvM_B1;
        } else {
            lB = midB + 1;
            pkA_B0 = pkM_B0; pkA_B1 = pkM_B1;
            pvA_B0 = pvM_B0; pvA_B1 = pvM_B1;
        }
        if (lev < LEVELS - 1) {
            midA = condA ? (midA - step) : (midA + step);
            midB = condB ? (midB - step) : (midB + step);
        }
    }

    float* opA = out + ((size_t)b * S + sA) * DIM + c;
    float* opB = out + ((size_t)b * S + sB) * DIM + c;
    *(float4*)opA       = ansA0;
    *(float4*)(opA + 4) = ansA1;
    *(float4*)opB       = ansB0;
    *(float4*)(opB + 4) = ansB1;
}

extern "C" void kernel_launch(void* const* d_in, const int* in_sizes, int n_in,
                              void* d_out, int out_size, void* d_ws, size_t ws_size,
                              hipStream_t stream) {
    const float* q    = (const float*)d_in[0];
    const float* keys = (const float*)d_in[1];
    const float* vals = (const float*)d_in[2];
    const int*   vl   = (const int*)d_in[3];
    float* out = (float*)d_out;

    const int B = in_sizes[3];                 // 16
    const int S = in_sizes[0] / (B * DIM);     // 8192

    dim3 grid(S / QPB, B);
    segtree_attn_kernel<<<grid, THREADS, 0, stream>>>(q, keys, vals, vl, out, S);
}

// Round 13
// 23.929 us; speedup vs baseline: 1.2712x; 1.1960x over previous
//
#include <hip/hip_runtime.h>
#include <math.h>

// SegmentTreeAttention — MI355X (gfx950), round 13.
// B=16, S=8192, D=64, N=32, LEVELS=5. f32 in/out. valid_lens per-batch.
//
// r12 (inline-Pv) regressed via VGPR -> reverted to r10 (24.6us best).
// Proven pattern: only instruction-count cuts on the r10 skeleton win.
// This round: COEFFICIENT-FOLDED GATHER.
//   sum_lev w*(Pv[hi]-Pv[lo]) == sum over <=7 distinct rows coef*Pv[row].
//   Each level finalizes exactly ONE frontier row (the replaced one), so
//   emissions go to STATIC slots rowE[lev], cE[lev] (+2 final frontiers).
//   Gather: 20 -> 14 b128 reads, 80 -> 56 FMA per query-pair.
// cond logic is bit-identical to r10 (div-free + gray rescue); the coef
// reassociation shifts the OUTPUT only by ~1e-5 (threshold 0.12).
// Keeps: QPB=64, 2-query ILP, DPP reduce, clamp identity, rcp weights,
// byte offsets, q-load hoist, no launch-bounds cap.

#define SEG_N   32
#define DIM     64
#define LEVELS  5
#define QPB     64      // queries per block
#define THREADS 256
#define PAD     68      // LDS row stride in dwords
#define PADB    (PAD * 4)

#define DPP_QUAD_XOR1   0xB1    // quad_perm [1,0,3,2]
#define DPP_QUAD_XOR2   0x4E    // quad_perm [2,3,0,1]
#define DPP_ROW_HMIRROR 0x141   // row_half_mirror (lane p -> 7-p within 8)

#if __has_builtin(__builtin_amdgcn_rcpf)
#define RCPF(x) __builtin_amdgcn_rcpf(x)
#else
#define RCPF(x) (1.0f / (x))
#endif

template <int CTRL>
__device__ __forceinline__ float dpp_xadd(float v) {
    const int s = __builtin_amdgcn_update_dpp(0, __float_as_int(v), CTRL, 0xf, 0xf, true);
    return v + __int_as_float(s);
}

// 8-lane group sum, all lanes get the bit-identical total.
__device__ __forceinline__ float group8_sum(float v) {
    v = dpp_xadd<DPP_QUAD_XOR1>(v);
    v = dpp_xadd<DPP_QUAD_XOR2>(v);
    v = dpp_xadd<DPP_ROW_HMIRROR>(v);
    return v;
}

__device__ __forceinline__ float4 f4sub(const float4 a, const float4 b) {
    return make_float4(a.x - b.x, a.y - b.y, a.z - b.z, a.w - b.w);
}
__device__ __forceinline__ float dot4(const float4 a, const float4 b) {
    return a.x * b.x + a.y * b.y + a.z * b.z + a.w * b.w;
}
// acc += v * w
__device__ __forceinline__ void fmaw(float4& acc, const float4 v, float w) {
    acc.x = fmaf(v.x, w, acc.x);
    acc.y = fmaf(v.y, w, acc.y);
    acc.z = fmaf(v.z, w, acc.z);
    acc.w = fmaf(v.w, w, acc.w);
}

__global__ __launch_bounds__(THREADS) void segtree_attn_kernel(
    const float* __restrict__ q,
    const float* __restrict__ keys,
    const float* __restrict__ values,
    const int*   __restrict__ vlen,
    float*       __restrict__ out,
    int S)
{
    __shared__ float P[2][SEG_N * PAD];   // P[0]=Pk, P[1]=Pv

    const int b = blockIdx.y;
    const int t = threadIdx.x;
    const int g = t >> 3;           // query group within block (0..31)
    const int u = t & 7;            // lane within group
    const int c = u * 8;            // column base (2x float4)
    const int c4 = c * 4;           // byte offset of column base

    const int sA = blockIdx.x * QPB + g;
    const int sB = sA + 32;

    // ---- q loads hoisted: latency hides under staging + barrier ----
    const float* qpA = q + ((size_t)b * S + sA) * DIM + c;
    const float* qpB = q + ((size_t)b * S + sB) * DIM + c;
    const float4 qA0 = *(const float4*)qpA;
    const float4 qA1 = *(const float4*)(qpA + 4);
    const float4 qB0 = *(const float4*)qpB;
    const float4 qB1 = *(const float4*)(qpB + 4);

    // ---- Stage prefix sums into LDS: P[0]=0, P[m]=sum_{l=1..m} x[l] ----
    if (t < 2 * DIM) {
        const int col = t & (DIM - 1);
        const float* src = ((t < DIM) ? keys : values) + (size_t)b * SEG_N * DIM + col;
        float* dst = (t < DIM) ? P[0] : P[1];
        float acc = 0.0f;
        dst[col] = 0.0f;
        #pragma unroll
        for (int row = 1; row < SEG_N; ++row) {
            acc += src[row * DIM];
            dst[row * PAD + col] = acc;
        }
    }
    const int n = vlen[b];          // block-uniform (valid_lens is [B])
    __syncthreads();

    const int hnc = max(min(n - 1, SEG_N - 1), 0);
    const float scale[LEVELS] = {0.0625f, 0.125f, 0.25f, 0.5f, 1.0f};
    const char* Kb = (const char*)&P[0][0];
    const char* Vb = (const char*)&P[1][0];

    // initial frontiers: P[l-1]=P[0]=0 ; P[clamp(min(r,n-1))] = P[hnc]
    const int offN = hnc * PADB + c4;
    float4 pkR_A0 = *(const float4*)(Kb + offN);
    float4 pkR_A1 = *(const float4*)(Kb + offN + 16);
    float4 pkR_B0 = pkR_A0, pkR_B1 = pkR_A1;
    float4 pkA_A0 = make_float4(0.f,0.f,0.f,0.f), pkA_A1 = make_float4(0.f,0.f,0.f,0.f);
    float4 pkA_B0 = make_float4(0.f,0.f,0.f,0.f), pkA_B1 = make_float4(0.f,0.f,0.f,0.f);

    int offA_A = c4, offR_A = offN;     // byte offsets of frontier rows
    int offA_B = c4, offR_B = offN;
    float cA_A = 0.0f, cR_A = 0.0f;     // running coefs of frontier rows
    float cA_B = 0.0f, cR_B = 0.0f;
    int midA = 16, midB = 16;
    int lA = 1, rA = SEG_N;
    int lB = 1, rB = SEG_N;

    // emissions: one finalized (row, coef) per level + 2 final frontiers
    float cE_A[LEVELS + 2], cE_B[LEVELS + 2];
    int   rowE_A[LEVELS + 2], rowE_B[LEVELS + 2];

    #pragma unroll
    for (int lev = 0; lev < LEVELS; ++lev) {
        const int step = 8 >> lev;
        const int cmA = min(midA, hnc);     // clamped row (clamp identity)
        const int cmB = min(midB, hnc);
        const int offMA = cmA * PADB + c4;
        const int offMB = cmB * PADB + c4;

        const float4 pkM_A0 = *(const float4*)(Kb + offMA);
        const float4 pkM_A1 = *(const float4*)(Kb + offMA + 16);
        const float4 pkM_B0 = *(const float4*)(Kb + offMB);
        const float4 pkM_B1 = *(const float4*)(Kb + offMB + 16);

        // subtract-then-dot (matches reference rounding structure)
        float dLA = dot4(qA0, f4sub(pkM_A0, pkA_A0)) + dot4(qA1, f4sub(pkM_A1, pkA_A1));
        float dRA = dot4(qA0, f4sub(pkR_A0, pkM_A0)) + dot4(qA1, f4sub(pkR_A1, pkM_A1));
        float dLB = dot4(qB0, f4sub(pkM_B0, pkA_B0)) + dot4(qB1, f4sub(pkM_B1, pkA_B1));
        float dRB = dot4(qB0, f4sub(pkR_B0, pkM_B0)) + dot4(qB1, f4sub(pkR_B1, pkM_B1));

        dLA = group8_sum(dLA);
        dRA = group8_sum(dRA);
        dLB = group8_sum(dLB);
        dRB = group8_sum(dRB);

        const bool okLA = (min(midA, n - 1) >= lA);
        const bool okRA = (min(rA,   n - 1) >= midA + 1);
        const bool okLB = (min(midB, n - 1) >= lB);
        const bool okRB = (min(rB,   n - 1) >= midB + 1);

        const float sLA = okLA ? dLA : 0.0f;
        const float sRA = okRA ? dRA : 0.0f;
        const float sLB = okLB ? dLB : 0.0f;
        const float sRB = okRB ? dRB : 0.0f;

        // sigmoid denominators (exact, same __expf as all passing rounds)
        const float dnLA = 1.0f + __expf(-sLA);
        const float dnRA = 1.0f + __expf(-sRA);
        const float dnLB = 1.0f + __expf(-sLB);
        const float dnRB = 1.0f + __expf(-sRB);

        // div-free cond with gray rescue (r10-validated, bit-exact)
        bool condA = (dnLA <= dnRA);
        bool condB = (dnLB <= dnRB);
        const bool grayA = (dnLA > dnRA) && ((dnLA - dnRA) < dnLA * 1e-6f);
        const bool grayB = (dnLB > dnRB) && ((dnLB - dnRB) < dnLB * 1e-6f);
        if (__any(grayA || grayB)) {        // P ~ 1e-5 per wave-level
            condA = ((1.0f / dnLA) >= (1.0f / dnRA));
            condB = ((1.0f / dnLB) >= (1.0f / dnRB));
        }

        const bool  okselA = condA ? okRA : okLA;
        const bool  okselB = condB ? okRB : okLB;
        const float wselA  = RCPF(condA ? dnRA : dnLA);  // weight: <=1ulp
        const float wselB  = RCPF(condB ? dnRB : dnLB);
        const float wAv = okselA ? (wselA * scale[lev]) : 0.0f;  // pow2: exact
        const float wBv = okselB ? (wselB * scale[lev]) : 0.0f;

        // ---- coefficient-folded emission (static slot = lev) ----
        // cond : +w -> rowR (finalize rowR, replaced by mid), mid starts -w
        // !cond: -w -> rowA (finalize rowA, replaced by mid), mid starts +w
        rowE_A[lev] = condA ? offR_A : offA_A;
        cE_A[lev]   = condA ? (cR_A + wAv) : (cA_A - wAv);
        rowE_B[lev] = condB ? offR_B : offA_B;
        cE_B[lev]   = condB ? (cR_B + wBv) : (cA_B - wBv);

        cR_A   = condA ? -wAv  : cR_A;
        cA_A   = condA ? cA_A  : wAv;
        offR_A = condA ? offMA : offR_A;
        offA_A = condA ? offA_A : offMA;
        cR_B   = condB ? -wBv  : cR_B;
        cA_B   = condB ? cA_B  : wBv;
        offR_B = condB ? offMB : offR_B;
        offA_B = condB ? offA_B : offMB;

        if (condA) {
            rA = midA;
            pkR_A0 = pkM_A0; pkR_A1 = pkM_A1;
        } else {
            lA = midA + 1;
            pkA_A0 = pkM_A0; pkA_A1 = pkM_A1;
        }
        if (condB) {
            rB = midB;
            pkR_B0 = pkM_B0; pkR_B1 = pkM_B1;
        } else {
            lB = midB + 1;
            pkA_B0 = pkM_B0; pkA_B1 = pkM_B1;
        }
        if (lev < LEVELS - 1) {
            midA = condA ? (midA - step) : (midA + step);
            midB = condB ? (midB - step) : (midB + step);
        }
    }

    // final frontier emissions
    rowE_A[LEVELS]     = offA_A;  cE_A[LEVELS]     = cA_A;
    rowE_A[LEVELS + 1] = offR_A;  cE_A[LEVELS + 1] = cR_A;
    rowE_B[LEVELS]     = offA_B;  cE_B[LEVELS]     = cA_B;
    rowE_B[LEVELS + 1] = offR_B;  cE_B[LEVELS + 1] = cR_B;

    // ---- folded gather: ans = sum_e coef_e * Pv[row_e]  (7 rows) ----
    float4 aA0 = make_float4(0.f,0.f,0.f,0.f), aA1 = make_float4(0.f,0.f,0.f,0.f);
    float4 aB0 = make_float4(0.f,0.f,0.f,0.f), aB1 = make_float4(0.f,0.f,0.f,0.f);
    #pragma unroll
    for (int e = 0; e < LEVELS + 2; ++e) {
        const float4 vA0 = *(const float4*)(Vb + rowE_A[e]);
        const float4 vA1 = *(const float4*)(Vb + rowE_A[e] + 16);
        fmaw(aA0, vA0, cE_A[e]);
        fmaw(aA1, vA1, cE_A[e]);
        const float4 vB0 = *(const float4*)(Vb + rowE_B[e]);
        const float4 vB1 = *(const float4*)(Vb + rowE_B[e] + 16);
        fmaw(aB0, vB0, cE_B[e]);
        fmaw(aB1, vB1, cE_B[e]);
    }

    float* opA = out + ((size_t)b * S + sA) * DIM + c;
    float* opB = out + ((size_t)b * S + sB) * DIM + c;
    *(float4*)opA       = aA0;
    *(float4*)(opA + 4) = aA1;
    *(float4*)opB       = aB0;
    *(float4*)(opB + 4) = aB1;
}

extern "C" void kernel_launch(void* const* d_in, const int* in_sizes, int n_in,
                              void* d_out, int out_size, void* d_ws, size_t ws_size,
                              hipStream_t stream) {
    const float* q    = (const float*)d_in[0];
    const float* keys = (const float*)d_in[1];
    const float* vals = (const float*)d_in[2];
    const int*   vl   = (const int*)d_in[3];
    float* out = (float*)d_out;

    const int B = in_sizes[3];                 // 16
    const int S = in_sizes[0] / (B * DIM);     // 8192

    dim3 grid(S / QPB, B);
    segtree_attn_kernel<<<grid, THREADS, 0, stream>>>(q, keys, vals, vl, out, S);
}